// Round 7
// baseline (163.431 us; speedup 1.0000x reference)
//
#include <hip/hip_runtime.h>

#define D 64
#define EPS 2.5e-4f      // >= ~3x the fp16-split worst-case score-error bound
#define INVSC 4.8828125e-4f   // 2^-11, exact

typedef __attribute__((ext_vector_type(8))) _Float16 f16x8;
typedef __attribute__((ext_vector_type(4))) float f32x4;

// prep: pre-swizzled fp16 hi/lo centroid images + c2 + zero counter.
// hi = fp16(c); lo = fp16((c - hi) * 2^11)  (scaling keeps lo normal-range).
// Layout per (step,r): 64 lanes x 16 B contiguous -> direct coalesced
// global_load_dwordx4 per B-fragment.
__global__ void prep_kernel(const float* __restrict__ c, _Float16* __restrict__ chs,
                            _Float16* __restrict__ cls, float* __restrict__ c2,
                            int K, int* __restrict__ counter) {
    int t = blockIdx.x * blockDim.x + threadIdx.x;
    if (t == 0) *counter = 0;
    const int nfr = K * 8;
    if (t < nfr) {
        const int k = t >> 3, f = t & 7;
        const int ks = f >> 2, quad = f & 3;
        const int chunk = k >> 6, kc = (k >> 4) & 3, col = k & 15;
        const size_t off = (size_t)chunk * 4096 +
                           (size_t)(((kc * 2 + ks) * 64 + quad * 16 + col) * 8);
        const float* src = c + (size_t)k * D + f * 8;
        f16x8 h, l;
#pragma unroll
        for (int j = 0; j < 8; ++j) {
            float x = src[j];
            _Float16 hs = (_Float16)x;
            h[j] = hs;
            l[j] = (_Float16)((x - (float)hs) * 2048.f);
        }
        *(f16x8*)(chs + off) = h;
        *(f16x8*)(cls + off) = l;
    }
    if (t < K) {
        const float4* cp = (const float4*)(c + (size_t)t * D);
        float s = 0.f;
#pragma unroll
        for (int i = 0; i < D / 4; ++i) {
            float4 v = cp[i];
            s += v.x * v.x; s += v.y * v.y; s += v.z * v.z; s += v.w * v.w;
        }
        c2[t] = s;
    }
}

// Pass 1: fp16-hi/lo MFMA scan + top-2 + bin write + near-tie flagging +
// exact fp32 residual.
// r6 lesson: 3 different staging structures all hit ~70 us at 8 waves/CU —
// no pipe >45% busy -> LATENCY-bound, and wave count was pinned by
// rows-per-wave (N/32 = 2048 waves). THIS REVISION splits K across waves:
// each wave keeps 32 rows but scans HALF of K (64 steps). 4096 waves =
// 16/CU (4/SIMD) at constant total MFMA/VMEM/VALU. The two K-half top-2
// sets merge in LDS with the same lexicographic (s,k) formula as the
// col-merge -> bit-identical results. Main loop (direct global->reg,
// depth-1 step pipeline, zero barriers) unchanged from r6.
__global__ __launch_bounds__(256, 4) void pass1_kernel(
    const float* __restrict__ action, const _Float16* __restrict__ chs,
    const _Float16* __restrict__ cls, const float* __restrict__ c2,
    const float* __restrict__ centroids, float* __restrict__ out_bin,
    float* __restrict__ out_res, int* __restrict__ counter,
    int* __restrict__ flags, int N, int K) {
    __shared__ float smb1[2][64], smb2[2][64];
    __shared__ int   smbk[2][64];
    __shared__ int   sbk[64];

    const int tid  = threadIdx.x;
    const int wv   = tid >> 6;
    const int kh   = wv >> 1;              // K-half this wave scans
    const int rg   = wv & 1;               // row-group this wave owns
    const int lane = tid & 63;
    const int col  = lane & 15;
    const int quad = lane >> 4;
    const int mb   = blockIdx.x * 64;
    const int m0   = mb + rg * 32;
    const int NTH  = K / 32;               // 64 steps per K-half
    const int t0   = kh * NTH;             // this wave's first step

    // B-fragment pointers in 16 B units: step t covers centroids
    // [16t, 16t+16); fragment index = t*128 + r*64 + lane.
    const f16x8* gh = (const f16x8*)chs;
    const f16x8* gl = (const f16x8*)cls;

#define LOADP(H0, H1, L0, L1, CC, t_)                                         \
    {                                                                         \
        const int cb = (t_) * 128 + lane;                                     \
        H0 = gh[cb];      H1 = gh[cb + 64];                                   \
        L0 = gl[cb];      L1 = gl[cb + 64];                                   \
        CC = c2[(t_) * 16 + col];                                             \
    }

    f16x8 p0h0, p0h1, p0l0, p0l1, p1h0, p1h1, p1l0, p1l1;
    float cc0, cc1;

    LOADP(p0h0, p0h1, p0l0, p0l1, cc0, t0)   // first step in flight under A-conv

    // A fragments: a' = -2a -> fp16 hi + scaled fp16 lo, in registers once.
    f16x8 ah[2][2], al[2][2];
#pragma unroll
    for (int mi = 0; mi < 2; ++mi) {
        const float* arow = action + (size_t)(m0 + mi * 16 + col) * D;
#pragma unroll
        for (int ks = 0; ks < 2; ++ks) {
            const float* src = arow + ks * 32 + quad * 8;
            f16x8 h, l;
#pragma unroll
            for (int j = 0; j < 8; ++j) {
                float x = -2.f * src[j];
                _Float16 hs = (_Float16)x;
                h[j] = hs;
                l[j] = (_Float16)((x - (float)hs) * 2048.f);
            }
            ah[mi][ks] = h;
            al[mi][ks] = l;
        }
    }

    float b1[8], b2[8];
    int   bk[8];
#pragma unroll
    for (int e = 0; e < 8; ++e) {
        b1[e] = __builtin_inff(); b2[e] = __builtin_inff(); bk[e] = 0;
    }

    const f32x4 z4 = {0.f, 0.f, 0.f, 0.f};   // persistent zero C-operand

#define COMPP(H0, H1, L0, L1, CC, t_)                                         \
    {                                                                         \
        const int kk = (t_) * 16 + col;                                       \
        const f32x4 cc4 = {CC, CC, CC, CC};                                   \
        _Pragma("unroll") for (int mi = 0; mi < 2; ++mi) {                    \
            __builtin_amdgcn_s_setprio(1);                                    \
            f32x4 acc2 = __builtin_amdgcn_mfma_f32_16x16x32_f16(al[mi][0], H0, z4, 0, 0, 0);   \
            acc2 = __builtin_amdgcn_mfma_f32_16x16x32_f16(ah[mi][0], L0, acc2, 0, 0, 0);       \
            f32x4 acc1 = __builtin_amdgcn_mfma_f32_16x16x32_f16(ah[mi][0], H0, cc4, 0, 0, 0);  \
            acc2 = __builtin_amdgcn_mfma_f32_16x16x32_f16(al[mi][1], H1, acc2, 0, 0, 0);       \
            acc2 = __builtin_amdgcn_mfma_f32_16x16x32_f16(ah[mi][1], L1, acc2, 0, 0, 0);       \
            acc1 = __builtin_amdgcn_mfma_f32_16x16x32_f16(ah[mi][1], H1, acc1, 0, 0, 0);       \
            __builtin_amdgcn_s_setprio(0);                                    \
            _Pragma("unroll") for (int r = 0; r < 4; ++r) {                   \
                const int e = mi * 4 + r;                                     \
                const float s = fmaf(INVSC, acc2[r], acc1[r]);                \
                b2[e] = __builtin_amdgcn_fmed3f(s, b1[e], b2[e]);             \
                const bool better = s < b1[e];                                \
                b1[e] = fminf(b1[e], s);                                      \
                bk[e] = better ? kk : bk[e];                                  \
            }                                                                 \
        }                                                                     \
    }

    for (int tl = 0; tl < NTH; tl += 2) {
        const int t = t0 + tl;
        LOADP(p1h0, p1h1, p1l0, p1l1, cc1, t + 1)     // prefetch t+1
        COMPP(p0h0, p0h1, p0l0, p0l1, cc0, t)
        {
            const int nt2 = (tl + 2 < NTH) ? (t + 2) : (t + 1);  // tail: dead
            LOADP(p0h0, p0h1, p0l0, p0l1, cc0, nt2)   // prefetch t+2
        }
        COMPP(p1h0, p1h1, p1l0, p1l1, cc1, t + 1)
    }
#undef COMPP
#undef LOADP

    // cross-lane top-2 merge over the 16 centroid columns (within K-half)
#pragma unroll
    for (int off = 1; off < 16; off <<= 1) {
#pragma unroll
        for (int e = 0; e < 8; ++e) {
            float o1 = __shfl_xor(b1[e], off, 64);
            float o2 = __shfl_xor(b2[e], off, 64);
            int   ok = __shfl_xor(bk[e], off, 64);
            bool take = (o1 < b1[e]) || (o1 == b1[e] && ok < bk[e]);
            float nb2 = take ? fminf(b1[e], o2) : fminf(b2[e], o1);
            b1[e] = take ? o1 : b1[e];
            bk[e] = take ? ok : bk[e];
            b2[e] = nb2;
        }
    }

    // per-half results -> LDS
    if (col == 0) {
#pragma unroll
        for (int e = 0; e < 8; ++e) {
            const int mi = e >> 2, r = e & 3;
            const int p = rg * 32 + mi * 16 + quad * 4 + r;   // 0..63
            smb1[kh][p] = b1[e];
            smb2[kh][p] = b2[e];
            smbk[kh][p] = bk[e];
        }
    }
    __syncthreads();

    // merge the two K-halves per point (same lexicographic (s,k) formula;
    // half 0 holds the lower k-range, so ties resolve to it naturally).
    if (tid < 64) {
        const int p = tid;
        float b1a = smb1[0][p], b2a = smb2[0][p];
        int   bka = smbk[0][p];
        float b1b = smb1[1][p], b2b = smb2[1][p];
        int   bkb = smbk[1][p];
        bool take = (b1b < b1a) || (b1b == b1a && bkb < bka);
        float m1 = take ? b1b : b1a;
        int   mk = take ? bkb : bka;
        float m2 = take ? fminf(b1a, b2b) : fminf(b2a, b1b);
        sbk[p] = mk;
        out_bin[mb + p] = (float)mk;
        if (m2 - m1 < EPS) {
            int idx = atomicAdd(counter, 1);
            flags[idx] = mb + p;
        }
    }
    __syncthreads();

    // exact fp32 residuals for the block's 64 points (1024 float4s).
    // 16 lanes per row -> 256 B contiguous centroid gather, coalesced I/O.
#pragma unroll
    for (int j = 0; j < 4; ++j) {
        const int idx = j * 256 + tid;
        const int row = idx >> 4, c4 = idx & 15;
        const int bki = sbk[row];
        float4 av = ((const float4*)(action + (size_t)(mb + row) * D))[c4];
        float4 cv = ((const float4*)centroids)[bki * 16 + c4];
        ((float4*)(out_res + (size_t)(mb + row) * D))[c4] =
            make_float4(av.x - cv.x, av.y - cv.y, av.z - cv.z, av.w - cv.w);
    }
}

// Exact fp32 rescan for flagged points. Block-per-point grid-stride,
// 4 interleaved dot accumulators for ILP. numpy first-min tie-break.
// (round-0 known-good version; count is ~10 so this is ~3 us)
__global__ __launch_bounds__(256) void exact_kernel(
    const float* __restrict__ action, const float* __restrict__ centroids,
    const float* __restrict__ c2, const int* __restrict__ counter,
    const int* __restrict__ flags, float* __restrict__ out_bin,
    float* __restrict__ out_res, int K) {
    __shared__ float4 sa[D / 4];
    __shared__ float  swv[4];
    __shared__ int    swk[4];
    __shared__ int    s_bk;
    const int count = *counter;
    const int tid = threadIdx.x, lane = tid & 63, wid = tid >> 6;
    for (int i = blockIdx.x; i < count; i += gridDim.x) {
        const int n = flags[i];
        __syncthreads();
        if (tid < D / 4) sa[tid] = ((const float4*)(action + (size_t)n * D))[tid];
        __syncthreads();
        float best = __builtin_inff();
        int bbk = 0x7fffffff;
        for (int k = tid; k < K; k += 256) {
            const float4* cr = (const float4*)(centroids + (size_t)k * D);
            float d0 = 0.f, d1 = 0.f, d2 = 0.f, d3 = 0.f;
#pragma unroll
            for (int q = 0; q < 4; ++q) {
                float4 a0 = sa[q * 4 + 0], c0 = cr[q * 4 + 0];
                float4 a1 = sa[q * 4 + 1], c1 = cr[q * 4 + 1];
                float4 a2 = sa[q * 4 + 2], c2v = cr[q * 4 + 2];
                float4 a3 = sa[q * 4 + 3], c3 = cr[q * 4 + 3];
                d0 = fmaf(a0.x, c0.x, d0); d0 = fmaf(a0.y, c0.y, d0);
                d0 = fmaf(a0.z, c0.z, d0); d0 = fmaf(a0.w, c0.w, d0);
                d1 = fmaf(a1.x, c1.x, d1); d1 = fmaf(a1.y, c1.y, d1);
                d1 = fmaf(a1.z, c1.z, d1); d1 = fmaf(a1.w, c1.w, d1);
                d2 = fmaf(a2.x, c2v.x, d2); d2 = fmaf(a2.y, c2v.y, d2);
                d2 = fmaf(a2.z, c2v.z, d2); d2 = fmaf(a2.w, c2v.w, d2);
                d3 = fmaf(a3.x, c3.x, d3); d3 = fmaf(a3.y, c3.y, d3);
                d3 = fmaf(a3.z, c3.z, d3); d3 = fmaf(a3.w, c3.w, d3);
            }
            float dot = (d0 + d1) + (d2 + d3);
            float s = fmaf(-2.f, dot, c2[k]);
            if (s < best) { best = s; bbk = k; }  // ascending k: first-min
        }
#pragma unroll
        for (int off = 32; off > 0; off >>= 1) {
            float ov = __shfl_down(best, off, 64);
            int   ok = __shfl_down(bbk, off, 64);
            if (ov < best || (ov == best && ok < bbk)) { best = ov; bbk = ok; }
        }
        if (lane == 0) { swv[wid] = best; swk[wid] = bbk; }
        __syncthreads();
        if (tid == 0) {
            float bb = swv[0]; int bki = swk[0];
#pragma unroll
            for (int t = 1; t < 4; ++t)
                if (swv[t] < bb || (swv[t] == bb && swk[t] < bki)) {
                    bb = swv[t]; bki = swk[t];
                }
            out_bin[n] = (float)bki;
            s_bk = bki;
        }
        __syncthreads();
        if (tid < D / 4) {
            float4 a = sa[tid];
            float4 c = ((const float4*)(centroids + (size_t)s_bk * D))[tid];
            ((float4*)(out_res + (size_t)n * D))[tid] =
                make_float4(a.x - c.x, a.y - c.y, a.z - c.z, a.w - c.w);
        }
    }
}

extern "C" void kernel_launch(void* const* d_in, const int* in_sizes, int n_in,
                              void* d_out, int out_size, void* d_ws, size_t ws_size,
                              hipStream_t stream) {
    const float* action    = (const float*)d_in[0];  // [N, 64]
    const float* centroids = (const float*)d_in[1];  // [K, 64]
    const int N = in_sizes[0] / D;  // 65536
    const int K = in_sizes[1] / D;  // 2048

    float* out_bin = (float*)d_out;      // N floats: argmin index
    float* out_res = (float*)d_out + N;  // N*D residuals

    // ws layout (~0.8 MB)
    char* w = (char*)d_ws;
    float*     c2      = (float*)w;                       // 8 KB
    int*       counter = (int*)(w + 8192);                // 4 B (padded to 256)
    int*       flags   = (int*)(w + 8448);                // N*4 = 256 KB
    _Float16*  chs     = (_Float16*)(w + 8448 + 262144);  // K*D*2 = 256 KB (swizzled)
    _Float16*  cls     = chs + (size_t)K * D;             // 256 KB (swizzled)

    prep_kernel<<<(K * 8 + 255) / 256, 256, 0, stream>>>(centroids, chs, cls,
                                                         c2, K, counter);
    pass1_kernel<<<N / 64, 256, 0, stream>>>(action, chs, cls, c2, centroids,
                                             out_bin, out_res, counter, flags,
                                             N, K);
    exact_kernel<<<256, 256, 0, stream>>>(action, centroids, c2, counter, flags,
                                          out_bin, out_res, K);
}

// Round 8
// 151.235 us; speedup vs baseline: 1.0806x; 1.0806x over previous
//
#include <hip/hip_runtime.h>

#define D 64
#define EPS 2.5e-4f      // >= ~3x the fp16-split worst-case score-error bound
#define INVSC 4.8828125e-4f   // 2^-11, exact

typedef __attribute__((ext_vector_type(8))) _Float16 f16x8;
typedef __attribute__((ext_vector_type(4))) float f32x4;

// prep: pre-swizzled fp16 hi/lo centroid images + c2 + zero counter.
// hi = fp16(c); lo = fp16((c - hi) * 2^11)  (scaling keeps lo normal-range).
// Layout per (step,r): 64 lanes x 16 B contiguous -> direct coalesced
// global_load_dwordx4 per B-fragment.
__global__ void prep_kernel(const float* __restrict__ c, _Float16* __restrict__ chs,
                            _Float16* __restrict__ cls, float* __restrict__ c2,
                            int K, int* __restrict__ counter) {
    int t = blockIdx.x * blockDim.x + threadIdx.x;
    if (t == 0) *counter = 0;
    const int nfr = K * 8;
    if (t < nfr) {
        const int k = t >> 3, f = t & 7;
        const int ks = f >> 2, quad = f & 3;
        const int chunk = k >> 6, kc = (k >> 4) & 3, col = k & 15;
        const size_t off = (size_t)chunk * 4096 +
                           (size_t)(((kc * 2 + ks) * 64 + quad * 16 + col) * 8);
        const float* src = c + (size_t)k * D + f * 8;
        f16x8 h, l;
#pragma unroll
        for (int j = 0; j < 8; ++j) {
            float x = src[j];
            _Float16 hs = (_Float16)x;
            h[j] = hs;
            l[j] = (_Float16)((x - (float)hs) * 2048.f);
        }
        *(f16x8*)(chs + off) = h;
        *(f16x8*)(cls + off) = l;
    }
    if (t < K) {
        const float4* cp = (const float4*)(c + (size_t)t * D);
        float s = 0.f;
#pragma unroll
        for (int i = 0; i < D / 4; ++i) {
            float4 v = cp[i];
            s += v.x * v.x; s += v.y * v.y; s += v.z * v.z; s += v.w * v.w;
        }
        c2[t] = s;
    }
}

// Pass 1: fp16-hi/lo MFMA scan + top-2 + bin write + near-tie flagging +
// exact fp32 residual.
// r7 falsified latency-bound (2x occupancy -> slower). r6/r7 invariant:
// ~25 B/cyc/CU of L1 return traffic in both -> vector-L1 path is the
// suspected saturated resource. THIS REVISION: 64 rows per wave (4 x 16-row
// MFMA tiles) so each loaded B-fragment feeds 2x the MFMAs -> total L1
// traffic halves at constant matrix work. Block = 128 rows x 2 K-halves
// (kh/rg wave split + LDS merge identical to the passing r7 scheme).
// Direct global->reg, depth-1 step pipeline, zero barriers in main loop.
__global__ __launch_bounds__(256, 2) void pass1_kernel(
    const float* __restrict__ action, const _Float16* __restrict__ chs,
    const _Float16* __restrict__ cls, const float* __restrict__ c2,
    const float* __restrict__ centroids, float* __restrict__ out_bin,
    float* __restrict__ out_res, int* __restrict__ counter,
    int* __restrict__ flags, int N, int K) {
    __shared__ float smb1[2][128], smb2[2][128];
    __shared__ int   smbk[2][128];
    __shared__ int   sbk[128];

    const int tid  = threadIdx.x;
    const int wv   = tid >> 6;
    const int kh   = wv >> 1;              // K-half this wave scans
    const int rg   = wv & 1;               // 64-row group this wave owns
    const int lane = tid & 63;
    const int col  = lane & 15;
    const int quad = lane >> 4;
    const int mb   = blockIdx.x * 128;
    const int m0   = mb + rg * 64;
    const int NTH  = K / 32;               // 64 steps per K-half
    const int t0   = kh * NTH;             // this wave's first step

    // B-fragment pointers in 16 B units: step t covers centroids
    // [16t, 16t+16); fragment index = t*128 + r*64 + lane.
    const f16x8* gh = (const f16x8*)chs;
    const f16x8* gl = (const f16x8*)cls;

#define LOADP(H0, H1, L0, L1, CC, t_)                                         \
    {                                                                         \
        const int cb = (t_) * 128 + lane;                                     \
        H0 = gh[cb];      H1 = gh[cb + 64];                                   \
        L0 = gl[cb];      L1 = gl[cb + 64];                                   \
        CC = c2[(t_) * 16 + col];                                             \
    }

    f16x8 p0h0, p0h1, p0l0, p0l1, p1h0, p1h1, p1l0, p1l1;
    float cc0, cc1;

    LOADP(p0h0, p0h1, p0l0, p0l1, cc0, t0)   // first step in flight under A-conv

    // A fragments: a' = -2a -> fp16 hi + scaled fp16 lo, in registers once.
    // 4 x 16-row tiles per wave.
    f16x8 ah[4][2], al[4][2];
#pragma unroll
    for (int mi = 0; mi < 4; ++mi) {
        const float* arow = action + (size_t)(m0 + mi * 16 + col) * D;
#pragma unroll
        for (int ks = 0; ks < 2; ++ks) {
            const float* src = arow + ks * 32 + quad * 8;
            f16x8 h, l;
#pragma unroll
            for (int j = 0; j < 8; ++j) {
                float x = -2.f * src[j];
                _Float16 hs = (_Float16)x;
                h[j] = hs;
                l[j] = (_Float16)((x - (float)hs) * 2048.f);
            }
            ah[mi][ks] = h;
            al[mi][ks] = l;
        }
    }

    float b1[16], b2[16];
    int   bk[16];
#pragma unroll
    for (int e = 0; e < 16; ++e) {
        b1[e] = __builtin_inff(); b2[e] = __builtin_inff(); bk[e] = 0;
    }

    const f32x4 z4 = {0.f, 0.f, 0.f, 0.f};   // persistent zero C-operand

#define COMPP(H0, H1, L0, L1, CC, t_)                                         \
    {                                                                         \
        const int kk = (t_) * 16 + col;                                       \
        const f32x4 cc4 = {CC, CC, CC, CC};                                   \
        _Pragma("unroll") for (int mi = 0; mi < 4; ++mi) {                    \
            __builtin_amdgcn_s_setprio(1);                                    \
            f32x4 acc2 = __builtin_amdgcn_mfma_f32_16x16x32_f16(al[mi][0], H0, z4, 0, 0, 0);   \
            acc2 = __builtin_amdgcn_mfma_f32_16x16x32_f16(ah[mi][0], L0, acc2, 0, 0, 0);       \
            f32x4 acc1 = __builtin_amdgcn_mfma_f32_16x16x32_f16(ah[mi][0], H0, cc4, 0, 0, 0);  \
            acc2 = __builtin_amdgcn_mfma_f32_16x16x32_f16(al[mi][1], H1, acc2, 0, 0, 0);       \
            acc2 = __builtin_amdgcn_mfma_f32_16x16x32_f16(ah[mi][1], L1, acc2, 0, 0, 0);       \
            acc1 = __builtin_amdgcn_mfma_f32_16x16x32_f16(ah[mi][1], H1, acc1, 0, 0, 0);       \
            __builtin_amdgcn_s_setprio(0);                                    \
            _Pragma("unroll") for (int r = 0; r < 4; ++r) {                   \
                const int e = mi * 4 + r;                                     \
                const float s = fmaf(INVSC, acc2[r], acc1[r]);                \
                b2[e] = __builtin_amdgcn_fmed3f(s, b1[e], b2[e]);             \
                const bool better = s < b1[e];                                \
                b1[e] = fminf(b1[e], s);                                      \
                bk[e] = better ? kk : bk[e];                                  \
            }                                                                 \
        }                                                                     \
    }

    for (int tl = 0; tl < NTH; tl += 2) {
        const int t = t0 + tl;
        LOADP(p1h0, p1h1, p1l0, p1l1, cc1, t + 1)     // prefetch t+1
        COMPP(p0h0, p0h1, p0l0, p0l1, cc0, t)
        {
            const int nt2 = (tl + 2 < NTH) ? (t + 2) : (t + 1);  // tail: dead
            LOADP(p0h0, p0h1, p0l0, p0l1, cc0, nt2)   // prefetch t+2
        }
        COMPP(p1h0, p1h1, p1l0, p1l1, cc1, t + 1)
    }
#undef COMPP
#undef LOADP

    // cross-lane top-2 merge over the 16 centroid columns (within K-half)
#pragma unroll
    for (int off = 1; off < 16; off <<= 1) {
#pragma unroll
        for (int e = 0; e < 16; ++e) {
            float o1 = __shfl_xor(b1[e], off, 64);
            float o2 = __shfl_xor(b2[e], off, 64);
            int   ok = __shfl_xor(bk[e], off, 64);
            bool take = (o1 < b1[e]) || (o1 == b1[e] && ok < bk[e]);
            float nb2 = take ? fminf(b1[e], o2) : fminf(b2[e], o1);
            b1[e] = take ? o1 : b1[e];
            bk[e] = take ? ok : bk[e];
            b2[e] = nb2;
        }
    }

    // per-half results -> LDS
    if (col == 0) {
#pragma unroll
        for (int e = 0; e < 16; ++e) {
            const int mi = e >> 2, r = e & 3;
            const int p = rg * 64 + mi * 16 + quad * 4 + r;   // 0..127
            smb1[kh][p] = b1[e];
            smb2[kh][p] = b2[e];
            smbk[kh][p] = bk[e];
        }
    }
    __syncthreads();

    // merge the two K-halves per point (same lexicographic (s,k) formula;
    // half 0 holds the lower k-range, so ties resolve to it naturally).
    if (tid < 128) {
        const int p = tid;
        float b1a = smb1[0][p], b2a = smb2[0][p];
        int   bka = smbk[0][p];
        float b1b = smb1[1][p], b2b = smb2[1][p];
        int   bkb = smbk[1][p];
        bool take = (b1b < b1a) || (b1b == b1a && bkb < bka);
        float m1 = take ? b1b : b1a;
        int   mk = take ? bkb : bka;
        float m2 = take ? fminf(b1a, b2b) : fminf(b2a, b1b);
        sbk[p] = mk;
        out_bin[mb + p] = (float)mk;
        if (m2 - m1 < EPS) {
            int idx = atomicAdd(counter, 1);
            flags[idx] = mb + p;
        }
    }
    __syncthreads();

    // exact fp32 residuals for the block's 128 points (2048 float4s).
    // 16 lanes per row -> 256 B contiguous centroid gather, coalesced I/O.
#pragma unroll
    for (int j = 0; j < 8; ++j) {
        const int idx = j * 256 + tid;
        const int row = idx >> 4, c4 = idx & 15;
        const int bki = sbk[row];
        float4 av = ((const float4*)(action + (size_t)(mb + row) * D))[c4];
        float4 cv = ((const float4*)centroids)[bki * 16 + c4];
        ((float4*)(out_res + (size_t)(mb + row) * D))[c4] =
            make_float4(av.x - cv.x, av.y - cv.y, av.z - cv.z, av.w - cv.w);
    }
}

// Exact fp32 rescan for flagged points. Block-per-point grid-stride,
// 4 interleaved dot accumulators for ILP. numpy first-min tie-break.
// (round-0 known-good version; count is ~10 so this is ~3 us)
__global__ __launch_bounds__(256) void exact_kernel(
    const float* __restrict__ action, const float* __restrict__ centroids,
    const float* __restrict__ c2, const int* __restrict__ counter,
    const int* __restrict__ flags, float* __restrict__ out_bin,
    float* __restrict__ out_res, int K) {
    __shared__ float4 sa[D / 4];
    __shared__ float  swv[4];
    __shared__ int    swk[4];
    __shared__ int    s_bk;
    const int count = *counter;
    const int tid = threadIdx.x, lane = tid & 63, wid = tid >> 6;
    for (int i = blockIdx.x; i < count; i += gridDim.x) {
        const int n = flags[i];
        __syncthreads();
        if (tid < D / 4) sa[tid] = ((const float4*)(action + (size_t)n * D))[tid];
        __syncthreads();
        float best = __builtin_inff();
        int bbk = 0x7fffffff;
        for (int k = tid; k < K; k += 256) {
            const float4* cr = (const float4*)(centroids + (size_t)k * D);
            float d0 = 0.f, d1 = 0.f, d2 = 0.f, d3 = 0.f;
#pragma unroll
            for (int q = 0; q < 4; ++q) {
                float4 a0 = sa[q * 4 + 0], c0 = cr[q * 4 + 0];
                float4 a1 = sa[q * 4 + 1], c1 = cr[q * 4 + 1];
                float4 a2 = sa[q * 4 + 2], c2v = cr[q * 4 + 2];
                float4 a3 = sa[q * 4 + 3], c3 = cr[q * 4 + 3];
                d0 = fmaf(a0.x, c0.x, d0); d0 = fmaf(a0.y, c0.y, d0);
                d0 = fmaf(a0.z, c0.z, d0); d0 = fmaf(a0.w, c0.w, d0);
                d1 = fmaf(a1.x, c1.x, d1); d1 = fmaf(a1.y, c1.y, d1);
                d1 = fmaf(a1.z, c1.z, d1); d1 = fmaf(a1.w, c1.w, d1);
                d2 = fmaf(a2.x, c2v.x, d2); d2 = fmaf(a2.y, c2v.y, d2);
                d2 = fmaf(a2.z, c2v.z, d2); d2 = fmaf(a2.w, c2v.w, d2);
                d3 = fmaf(a3.x, c3.x, d3); d3 = fmaf(a3.y, c3.y, d3);
                d3 = fmaf(a3.z, c3.z, d3); d3 = fmaf(a3.w, c3.w, d3);
            }
            float dot = (d0 + d1) + (d2 + d3);
            float s = fmaf(-2.f, dot, c2[k]);
            if (s < best) { best = s; bbk = k; }  // ascending k: first-min
        }
#pragma unroll
        for (int off = 32; off > 0; off >>= 1) {
            float ov = __shfl_down(best, off, 64);
            int   ok = __shfl_down(bbk, off, 64);
            if (ov < best || (ov == best && ok < bbk)) { best = ov; bbk = ok; }
        }
        if (lane == 0) { swv[wid] = best; swk[wid] = bbk; }
        __syncthreads();
        if (tid == 0) {
            float bb = swv[0]; int bki = swk[0];
#pragma unroll
            for (int t = 1; t < 4; ++t)
                if (swv[t] < bb || (swv[t] == bb && swk[t] < bki)) {
                    bb = swv[t]; bki = swk[t];
                }
            out_bin[n] = (float)bki;
            s_bk = bki;
        }
        __syncthreads();
        if (tid < D / 4) {
            float4 a = sa[tid];
            float4 c = ((const float4*)(centroids + (size_t)s_bk * D))[tid];
            ((float4*)(out_res + (size_t)n * D))[tid] =
                make_float4(a.x - c.x, a.y - c.y, a.z - c.z, a.w - c.w);
        }
    }
}

extern "C" void kernel_launch(void* const* d_in, const int* in_sizes, int n_in,
                              void* d_out, int out_size, void* d_ws, size_t ws_size,
                              hipStream_t stream) {
    const float* action    = (const float*)d_in[0];  // [N, 64]
    const float* centroids = (const float*)d_in[1];  // [K, 64]
    const int N = in_sizes[0] / D;  // 65536
    const int K = in_sizes[1] / D;  // 2048

    float* out_bin = (float*)d_out;      // N floats: argmin index
    float* out_res = (float*)d_out + N;  // N*D residuals

    // ws layout (~0.8 MB)
    char* w = (char*)d_ws;
    float*     c2      = (float*)w;                       // 8 KB
    int*       counter = (int*)(w + 8192);                // 4 B (padded to 256)
    int*       flags   = (int*)(w + 8448);                // N*4 = 256 KB
    _Float16*  chs     = (_Float16*)(w + 8448 + 262144);  // K*D*2 = 256 KB (swizzled)
    _Float16*  cls     = chs + (size_t)K * D;             // 256 KB (swizzled)

    prep_kernel<<<(K * 8 + 255) / 256, 256, 0, stream>>>(centroids, chs, cls,
                                                         c2, K, counter);
    pass1_kernel<<<N / 128, 256, 0, stream>>>(action, chs, cls, c2, centroids,
                                              out_bin, out_res, counter, flags,
                                              N, K);
    exact_kernel<<<256, 256, 0, stream>>>(action, centroids, c2, counter, flags,
                                          out_bin, out_res, K);
}

// Round 9
// 143.633 us; speedup vs baseline: 1.1378x; 1.0529x over previous
//
#include <hip/hip_runtime.h>

#define D 64
#define EPS 2.0e-3f      // >= ~4x the merged-chain worst-case score-error bound
                         // (6 fp32 roundings at |acc|~1e3 + fp16-split terms ~4.4e-4)

typedef __attribute__((ext_vector_type(8))) _Float16 f16x8;
typedef __attribute__((ext_vector_type(4))) float f32x4;

// prep: pre-swizzled fp16 hi/lo centroid images + c2 + zero counter.
// hi = fp16(c); lo = fp16(c - hi)  (UNscaled: values ~5e-4 are fp16-normal
// for |c|>0.12, denormal below; CDNA4 MFMA f16 supports denorm inputs).
// Layout per (step,r): 64 lanes x 16 B contiguous -> direct coalesced
// global_load_dwordx4 per B-fragment.
__global__ void prep_kernel(const float* __restrict__ c, _Float16* __restrict__ chs,
                            _Float16* __restrict__ cls, float* __restrict__ c2,
                            int K, int* __restrict__ counter) {
    int t = blockIdx.x * blockDim.x + threadIdx.x;
    if (t == 0) *counter = 0;
    const int nfr = K * 8;
    if (t < nfr) {
        const int k = t >> 3, f = t & 7;
        const int ks = f >> 2, quad = f & 3;
        const int chunk = k >> 6, kc = (k >> 4) & 3, col = k & 15;
        const size_t off = (size_t)chunk * 4096 +
                           (size_t)(((kc * 2 + ks) * 64 + quad * 16 + col) * 8);
        const float* src = c + (size_t)k * D + f * 8;
        f16x8 h, l;
#pragma unroll
        for (int j = 0; j < 8; ++j) {
            float x = src[j];
            _Float16 hs = (_Float16)x;
            h[j] = hs;
            l[j] = (_Float16)(x - (float)hs);    // unscaled lo
        }
        *(f16x8*)(chs + off) = h;
        *(f16x8*)(cls + off) = l;
    }
    if (t < K) {
        const float4* cp = (const float4*)(c + (size_t)t * D);
        float s = 0.f;
#pragma unroll
        for (int i = 0; i < D / 4; ++i) {
            float4 v = cp[i];
            s += v.x * v.x; s += v.y * v.y; s += v.z * v.z; s += v.w * v.w;
        }
        c2[t] = s;
    }
}

// Pass 1: fp16-hi/lo MFMA scan + top-2 + bin write + near-tie flagging +
// exact fp32 residual.
// r8 diagnosis: five structures all ~70 us; MFMA cycles + fold-VALU cycles
// ADD on the SIMD (shared issue), so the lever is ops-per-score.
// THIS REVISION: single 6-MFMA accumulator chain per tile (lo stored
// unscaled -> no INVSC fmaf combine; acc2/z4 gone). Fold = 4 ops/score
// (med3, cmp, min, cndmask). EPS widened to 2e-3 for the merged-chain
// rounding; flag count ~60, exact_kernel still one round.
// Structure otherwise identical to r8: 64 rows/wave (4 x 16-row tiles),
// 128-row block x 2 K-halves (kh/rg split + LDS merge), direct global->reg
// B loads, depth-1 step pipeline, zero barriers in the main loop.
__global__ __launch_bounds__(256, 2) void pass1_kernel(
    const float* __restrict__ action, const _Float16* __restrict__ chs,
    const _Float16* __restrict__ cls, const float* __restrict__ c2,
    const float* __restrict__ centroids, float* __restrict__ out_bin,
    float* __restrict__ out_res, int* __restrict__ counter,
    int* __restrict__ flags, int N, int K) {
    __shared__ float smb1[2][128], smb2[2][128];
    __shared__ int   smbk[2][128];
    __shared__ int   sbk[128];

    const int tid  = threadIdx.x;
    const int wv   = tid >> 6;
    const int kh   = wv >> 1;              // K-half this wave scans
    const int rg   = wv & 1;               // 64-row group this wave owns
    const int lane = tid & 63;
    const int col  = lane & 15;
    const int quad = lane >> 4;
    const int mb   = blockIdx.x * 128;
    const int m0   = mb + rg * 64;
    const int NTH  = K / 32;               // 64 steps per K-half
    const int t0   = kh * NTH;             // this wave's first step

    // B-fragment pointers in 16 B units: step t covers centroids
    // [16t, 16t+16); fragment index = t*128 + r*64 + lane.
    const f16x8* gh = (const f16x8*)chs;
    const f16x8* gl = (const f16x8*)cls;

#define LOADP(H0, H1, L0, L1, CC, t_)                                         \
    {                                                                         \
        const int cb = (t_) * 128 + lane;                                     \
        H0 = gh[cb];      H1 = gh[cb + 64];                                   \
        L0 = gl[cb];      L1 = gl[cb + 64];                                   \
        CC = c2[(t_) * 16 + col];                                             \
    }

    f16x8 p0h0, p0h1, p0l0, p0l1, p1h0, p1h1, p1l0, p1l1;
    float cc0, cc1;

    LOADP(p0h0, p0h1, p0l0, p0l1, cc0, t0)   // first step in flight under A-conv

    // A fragments: a' = -2a -> fp16 hi + unscaled fp16 lo, in registers once.
    // 4 x 16-row tiles per wave.
    f16x8 ah[4][2], al[4][2];
#pragma unroll
    for (int mi = 0; mi < 4; ++mi) {
        const float* arow = action + (size_t)(m0 + mi * 16 + col) * D;
#pragma unroll
        for (int ks = 0; ks < 2; ++ks) {
            const float* src = arow + ks * 32 + quad * 8;
            f16x8 h, l;
#pragma unroll
            for (int j = 0; j < 8; ++j) {
                float x = -2.f * src[j];
                _Float16 hs = (_Float16)x;
                h[j] = hs;
                l[j] = (_Float16)(x - (float)hs);    // unscaled lo
            }
            ah[mi][ks] = h;
            al[mi][ks] = l;
        }
    }

    float b1[16], b2[16];
    int   bk[16];
#pragma unroll
    for (int e = 0; e < 16; ++e) {
        b1[e] = __builtin_inff(); b2[e] = __builtin_inff(); bk[e] = 0;
    }

#define COMPP(H0, H1, L0, L1, CC, t_)                                         \
    {                                                                         \
        const int kk = (t_) * 16 + col;                                       \
        const f32x4 cc4 = {CC, CC, CC, CC};                                   \
        _Pragma("unroll") for (int mi = 0; mi < 4; ++mi) {                    \
            __builtin_amdgcn_s_setprio(1);                                    \
            f32x4 acc = __builtin_amdgcn_mfma_f32_16x16x32_f16(ah[mi][0], H0, cc4, 0, 0, 0);  \
            acc = __builtin_amdgcn_mfma_f32_16x16x32_f16(ah[mi][0], L0, acc, 0, 0, 0);        \
            acc = __builtin_amdgcn_mfma_f32_16x16x32_f16(al[mi][0], H0, acc, 0, 0, 0);        \
            acc = __builtin_amdgcn_mfma_f32_16x16x32_f16(ah[mi][1], H1, acc, 0, 0, 0);        \
            acc = __builtin_amdgcn_mfma_f32_16x16x32_f16(ah[mi][1], L1, acc, 0, 0, 0);        \
            acc = __builtin_amdgcn_mfma_f32_16x16x32_f16(al[mi][1], H1, acc, 0, 0, 0);        \
            __builtin_amdgcn_s_setprio(0);                                    \
            _Pragma("unroll") for (int r = 0; r < 4; ++r) {                   \
                const int e = mi * 4 + r;                                     \
                const float s = acc[r];                                       \
                b2[e] = __builtin_amdgcn_fmed3f(s, b1[e], b2[e]);             \
                const bool better = s < b1[e];                                \
                b1[e] = fminf(b1[e], s);                                      \
                bk[e] = better ? kk : bk[e];                                  \
            }                                                                 \
        }                                                                     \
    }

    for (int tl = 0; tl < NTH; tl += 2) {
        const int t = t0 + tl;
        LOADP(p1h0, p1h1, p1l0, p1l1, cc1, t + 1)     // prefetch t+1
        COMPP(p0h0, p0h1, p0l0, p0l1, cc0, t)
        {
            const int nt2 = (tl + 2 < NTH) ? (t + 2) : (t + 1);  // tail: dead
            LOADP(p0h0, p0h1, p0l0, p0l1, cc0, nt2)   // prefetch t+2
        }
        COMPP(p1h0, p1h1, p1l0, p1l1, cc1, t + 1)
    }
#undef COMPP
#undef LOADP

    // cross-lane top-2 merge over the 16 centroid columns (within K-half)
#pragma unroll
    for (int off = 1; off < 16; off <<= 1) {
#pragma unroll
        for (int e = 0; e < 16; ++e) {
            float o1 = __shfl_xor(b1[e], off, 64);
            float o2 = __shfl_xor(b2[e], off, 64);
            int   ok = __shfl_xor(bk[e], off, 64);
            bool take = (o1 < b1[e]) || (o1 == b1[e] && ok < bk[e]);
            float nb2 = take ? fminf(b1[e], o2) : fminf(b2[e], o1);
            b1[e] = take ? o1 : b1[e];
            bk[e] = take ? ok : bk[e];
            b2[e] = nb2;
        }
    }

    // per-half results -> LDS
    if (col == 0) {
#pragma unroll
        for (int e = 0; e < 16; ++e) {
            const int mi = e >> 2, r = e & 3;
            const int p = rg * 64 + mi * 16 + quad * 4 + r;   // 0..127
            smb1[kh][p] = b1[e];
            smb2[kh][p] = b2[e];
            smbk[kh][p] = bk[e];
        }
    }
    __syncthreads();

    // merge the two K-halves per point (same lexicographic (s,k) formula;
    // half 0 holds the lower k-range, so ties resolve to it naturally).
    if (tid < 128) {
        const int p = tid;
        float b1a = smb1[0][p], b2a = smb2[0][p];
        int   bka = smbk[0][p];
        float b1b = smb1[1][p], b2b = smb2[1][p];
        int   bkb = smbk[1][p];
        bool take = (b1b < b1a) || (b1b == b1a && bkb < bka);
        float m1 = take ? b1b : b1a;
        int   mk = take ? bkb : bka;
        float m2 = take ? fminf(b1a, b2b) : fminf(b2a, b1b);
        sbk[p] = mk;
        out_bin[mb + p] = (float)mk;
        if (m2 - m1 < EPS) {
            int idx = atomicAdd(counter, 1);
            flags[idx] = mb + p;
        }
    }
    __syncthreads();

    // exact fp32 residuals for the block's 128 points (2048 float4s).
    // 16 lanes per row -> 256 B contiguous centroid gather, coalesced I/O.
#pragma unroll
    for (int j = 0; j < 8; ++j) {
        const int idx = j * 256 + tid;
        const int row = idx >> 4, c4 = idx & 15;
        const int bki = sbk[row];
        float4 av = ((const float4*)(action + (size_t)(mb + row) * D))[c4];
        float4 cv = ((const float4*)centroids)[bki * 16 + c4];
        ((float4*)(out_res + (size_t)(mb + row) * D))[c4] =
            make_float4(av.x - cv.x, av.y - cv.y, av.z - cv.z, av.w - cv.w);
    }
}

// Exact fp32 rescan for flagged points. Block-per-point grid-stride,
// 4 interleaved dot accumulators for ILP. numpy first-min tie-break.
// (round-0 known-good version; count ~60 at the widened EPS -> ~4 us)
__global__ __launch_bounds__(256) void exact_kernel(
    const float* __restrict__ action, const float* __restrict__ centroids,
    const float* __restrict__ c2, const int* __restrict__ counter,
    const int* __restrict__ flags, float* __restrict__ out_bin,
    float* __restrict__ out_res, int K) {
    __shared__ float4 sa[D / 4];
    __shared__ float  swv[4];
    __shared__ int    swk[4];
    __shared__ int    s_bk;
    const int count = *counter;
    const int tid = threadIdx.x, lane = tid & 63, wid = tid >> 6;
    for (int i = blockIdx.x; i < count; i += gridDim.x) {
        const int n = flags[i];
        __syncthreads();
        if (tid < D / 4) sa[tid] = ((const float4*)(action + (size_t)n * D))[tid];
        __syncthreads();
        float best = __builtin_inff();
        int bbk = 0x7fffffff;
        for (int k = tid; k < K; k += 256) {
            const float4* cr = (const float4*)(centroids + (size_t)k * D);
            float d0 = 0.f, d1 = 0.f, d2 = 0.f, d3 = 0.f;
#pragma unroll
            for (int q = 0; q < 4; ++q) {
                float4 a0 = sa[q * 4 + 0], c0 = cr[q * 4 + 0];
                float4 a1 = sa[q * 4 + 1], c1 = cr[q * 4 + 1];
                float4 a2 = sa[q * 4 + 2], c2v = cr[q * 4 + 2];
                float4 a3 = sa[q * 4 + 3], c3 = cr[q * 4 + 3];
                d0 = fmaf(a0.x, c0.x, d0); d0 = fmaf(a0.y, c0.y, d0);
                d0 = fmaf(a0.z, c0.z, d0); d0 = fmaf(a0.w, c0.w, d0);
                d1 = fmaf(a1.x, c1.x, d1); d1 = fmaf(a1.y, c1.y, d1);
                d1 = fmaf(a1.z, c1.z, d1); d1 = fmaf(a1.w, c1.w, d1);
                d2 = fmaf(a2.x, c2v.x, d2); d2 = fmaf(a2.y, c2v.y, d2);
                d2 = fmaf(a2.z, c2v.z, d2); d2 = fmaf(a2.w, c2v.w, d2);
                d3 = fmaf(a3.x, c3.x, d3); d3 = fmaf(a3.y, c3.y, d3);
                d3 = fmaf(a3.z, c3.z, d3); d3 = fmaf(a3.w, c3.w, d3);
            }
            float dot = (d0 + d1) + (d2 + d3);
            float s = fmaf(-2.f, dot, c2[k]);
            if (s < best) { best = s; bbk = k; }  // ascending k: first-min
        }
#pragma unroll
        for (int off = 32; off > 0; off >>= 1) {
            float ov = __shfl_down(best, off, 64);
            int   ok = __shfl_down(bbk, off, 64);
            if (ov < best || (ov == best && ok < bbk)) { best = ov; bbk = ok; }
        }
        if (lane == 0) { swv[wid] = best; swk[wid] = bbk; }
        __syncthreads();
        if (tid == 0) {
            float bb = swv[0]; int bki = swk[0];
#pragma unroll
            for (int t = 1; t < 4; ++t)
                if (swv[t] < bb || (swv[t] == bb && swk[t] < bki)) {
                    bb = swv[t]; bki = swk[t];
                }
            out_bin[n] = (float)bki;
            s_bk = bki;
        }
        __syncthreads();
        if (tid < D / 4) {
            float4 a = sa[tid];
            float4 c = ((const float4*)(centroids + (size_t)s_bk * D))[tid];
            ((float4*)(out_res + (size_t)n * D))[tid] =
                make_float4(a.x - c.x, a.y - c.y, a.z - c.z, a.w - c.w);
        }
    }
}

extern "C" void kernel_launch(void* const* d_in, const int* in_sizes, int n_in,
                              void* d_out, int out_size, void* d_ws, size_t ws_size,
                              hipStream_t stream) {
    const float* action    = (const float*)d_in[0];  // [N, 64]
    const float* centroids = (const float*)d_in[1];  // [K, 64]
    const int N = in_sizes[0] / D;  // 65536
    const int K = in_sizes[1] / D;  // 2048

    float* out_bin = (float*)d_out;      // N floats: argmin index
    float* out_res = (float*)d_out + N;  // N*D residuals

    // ws layout (~0.8 MB)
    char* w = (char*)d_ws;
    float*     c2      = (float*)w;                       // 8 KB
    int*       counter = (int*)(w + 8192);                // 4 B (padded to 256)
    int*       flags   = (int*)(w + 8448);                // N*4 = 256 KB
    _Float16*  chs     = (_Float16*)(w + 8448 + 262144);  // K*D*2 = 256 KB (swizzled)
    _Float16*  cls     = chs + (size_t)K * D;             // 256 KB (swizzled)

    prep_kernel<<<(K * 8 + 255) / 256, 256, 0, stream>>>(centroids, chs, cls,
                                                         c2, K, counter);
    pass1_kernel<<<N / 128, 256, 0, stream>>>(action, chs, cls, c2, centroids,
                                              out_bin, out_res, counter, flags,
                                              N, K);
    exact_kernel<<<256, 256, 0, stream>>>(action, centroids, c2, counter, flags,
                                          out_bin, out_res, K);
}